// Round 6
// baseline (297.798 us; speedup 1.0000x reference)
//
#include <hip/hip_runtime.h>
#include <hip/hip_fp16.h>

// CausalSelfAttention: B=4 S=2048 D=1024 H=16 HD=64, scale = HD^0.25 (quirk), f32 io.
// Pipeline: cvt(f32->f16) -> fused QKV gemm (V written transposed [b][h][d][s])
//           -> flash attention (swapped-operand, paired q-tiles, 2-phase LDS dbuf)
//           -> output gemm (f32 out + bias).
// R6: GEMMs get 2-phase dbuf (T3 minimum), XCD-chunked block swizzle (T1),
//     and LDS chunk swizzle c^=(row>>1)&3 on both stage-source and frag-read (T2).

typedef unsigned short u16;
typedef unsigned int u32;
typedef _Float16 half8 __attribute__((ext_vector_type(8)));
typedef float f32x4 __attribute__((ext_vector_type(4)));
typedef unsigned short ushort8 __attribute__((ext_vector_type(8)));
typedef unsigned short us4 __attribute__((ext_vector_type(4)));
typedef unsigned int u32x2 __attribute__((ext_vector_type(2)));

#define SCL2 4.0816663172343815f /* 64^0.25 * log2(e) */
#define SWZ(r) ((((r) ^ ((r) >> 3))) & 7)

__device__ __forceinline__ u16 f2h(float f) {
  return __half_as_ushort(__float2half(f));
}

// packed f32->f16 (rtz) x4 -> 8 bytes
__device__ __forceinline__ us4 pack4(float a, float b, float c, float d) {
  u32x2 t;
  t[0] = __builtin_bit_cast(u32, __builtin_amdgcn_cvt_pkrtz(a, b));
  t[1] = __builtin_bit_cast(u32, __builtin_amdgcn_cvt_pkrtz(c, d));
  return __builtin_bit_cast(us4, t);
}

__device__ __forceinline__ void gload16(const void* gsrc, void* ldst) {
  typedef __attribute__((address_space(1))) const void glob_t;
  typedef __attribute__((address_space(3))) void lds_t;
  __builtin_amdgcn_global_load_lds((glob_t*)gsrc, (lds_t*)ldst, 16, 0, 0);
}

__device__ __forceinline__ f32x4 mfma_f16(half8 a, half8 b, f32x4 c) {
  return __builtin_amdgcn_mfma_f32_16x16x32_f16(a, b, c, 0, 0, 0);
}

// ---------------- f32 -> f16 convert, 8 elements/thread ----------------
__global__ __launch_bounds__(256) void cvt_f32_f16(const float* __restrict__ in,
                                                   u16* __restrict__ out, int n8) {
  int i = blockIdx.x * 256 + threadIdx.x;
  if (i >= n8) return;
  const float4* p = (const float4*)in + (size_t)i * 2;
  float4 a = p[0], b = p[1];
  ushort8 v;
  v[0] = f2h(a.x); v[1] = f2h(a.y); v[2] = f2h(a.z); v[3] = f2h(a.w);
  v[4] = f2h(b.x); v[5] = f2h(b.y); v[6] = f2h(b.z); v[7] = f2h(b.w);
  *(ushort8*)(out + (size_t)i * 8) = v;
}

// ---------------- GEMM: C[M=8192,N=1024] = A[M,K=1024] * Bw[N,K]^T + bias ----------------
// 128x128 tile, BK=32, 256 threads (4 waves, 2x2 of 64x64), 2-phase LDS dbuf,
// single barrier per K-step. LDS chunk swizzle: chunk c of row r stored at c^((r>>1)&3).
// Epilogues: Ch = f16 row-major [token][1024]; Cf = f32 row-major; Vtp = f16 [b][h][d][s].
__device__ __forceinline__ void gemm_body(const u16* __restrict__ A, const u16* __restrict__ Bw,
                                          const float* __restrict__ bias,
                                          u16* __restrict__ Ch, float* __restrict__ Cf,
                                          u16* __restrict__ Vtp, int m0, int n0) {
  __shared__ __align__(16) u16 sA[2][128 * 32];
  __shared__ __align__(16) u16 sB[2][128 * 32];
  const int tid = threadIdx.x, w = tid >> 6, l = tid & 63;
  const int wm = (w >> 1) * 64, wn = (w & 1) * 64;
  f32x4 acc[4][4] = {};
  const int srow = tid >> 2;
  const int sch = ((tid & 3) ^ ((srow >> 1) & 3)) * 8;  // swizzled source chunk
  const u16* Ag0 = A + (size_t)(m0 + srow) * 1024 + sch;
  const u16* Ag1 = A + (size_t)(m0 + 64 + srow) * 1024 + sch;
  const u16* Bg0 = Bw + (size_t)(n0 + srow) * 1024 + sch;
  const u16* Bg1 = Bw + (size_t)(n0 + 64 + srow) * 1024 + sch;
  auto stage = [&](int buf, int k0) {
    char* a = (char*)sA[buf] + w * 1024;
    char* b = (char*)sB[buf] + w * 1024;
    gload16(Ag0 + k0, a);
    gload16(Ag1 + k0, a + 4096);
    gload16(Bg0 + k0, b);
    gload16(Bg1 + k0, b + 4096);
  };
  stage(0, 0);
  __syncthreads();
  int cur = 0;
  // frag read: logical chunk (l>>4) of row (..+(l&15)) lives at chunk^((row>>1)&3)
  const int ca = ((l >> 4) ^ (((l & 15) >> 1) & 3)) * 8;
  for (int kt = 0; kt < 32; ++kt) {
    if (kt < 31) stage(cur ^ 1, (kt + 1) * 32);  // issue-early: next tile in flight
    half8 a[4], b[4];
#pragma unroll
    for (int mf = 0; mf < 4; ++mf)
      a[mf] = *(const half8*)&sA[cur][(wm + mf * 16 + (l & 15)) * 32 + ca];
#pragma unroll
    for (int nf = 0; nf < 4; ++nf)
      b[nf] = *(const half8*)&sB[cur][(wn + nf * 16 + (l & 15)) * 32 + ca];
#pragma unroll
    for (int mf = 0; mf < 4; ++mf)
#pragma unroll
      for (int nf = 0; nf < 4; ++nf)
        acc[mf][nf] = mfma_f16(a[mf], b[nf], acc[mf][nf]);
    __syncthreads();  // single sync/K-step: drains own prefetch AFTER compute
    cur ^= 1;
  }
  if (Vtp) {
    // V^T epilogue: Vt[(b*16+h)][d][s], 4 consecutive s (r=0..3) -> ushort4 store.
#pragma unroll
    for (int nf = 0; nf < 4; ++nf) {
      const int col = n0 + wn + nf * 16 + (l & 15);  // d_model = h*64+d
      const float bv = bias[col];
#pragma unroll
      for (int mf = 0; mf < 4; ++mf) {
        const int row = m0 + wm + mf * 16 + (l >> 4) * 4;  // token = b*2048+s
        us4 v;
#pragma unroll
        for (int r = 0; r < 4; ++r) v[r] = f2h(acc[mf][nf][r] + bv);
        *(us4*)(Vtp + (size_t)((row >> 11) * 16 + (col >> 6)) * 131072 +
                (size_t)(col & 63) * 2048 + (row & 2047)) = v;
      }
    }
  } else {
#pragma unroll
    for (int nf = 0; nf < 4; ++nf) {
      const int col = n0 + wn + nf * 16 + (l & 15);
      const float bv = bias[col];
#pragma unroll
      for (int mf = 0; mf < 4; ++mf) {
#pragma unroll
        for (int r = 0; r < 4; ++r) {
          const int row = m0 + wm + mf * 16 + (l >> 4) * 4 + r;
          float v = acc[mf][nf][r] + bv;
          if (Cf) Cf[(size_t)row * 1024 + col] = v;
          else    Ch[(size_t)row * 1024 + col] = f2h(v);
        }
      }
    }
  }
}

struct QkvArgs {
  const u16* B[3];
  const float* bias[3];
  u16* C[3];
};

// XCD-chunked swizzle (T1): hw linear id lin -> xcd = lin&7 (dispatch round-robin),
// give each XCD a contiguous work chunk; within chunk, m-panel major so the 24
// blocks (8 n x 3 z) sharing an A-panel run on ONE XCD's L2.
__global__ __launch_bounds__(256) void gemm_qkv(const u16* __restrict__ A, QkvArgs ga) {
  const int lin = blockIdx.x;                    // 0..1535
  const int wid = (lin & 7) * 192 + (lin >> 3);  // bijective: 1536 = 8*192
  const int mblk = wid / 24;                     // 0..63
  const int rem = wid - mblk * 24;
  const int z = rem >> 3, nblk = rem & 7;
  if (z == 2) gemm_body(A, ga.B[2], ga.bias[2], nullptr, nullptr, ga.C[2], mblk * 128, nblk * 128);
  else        gemm_body(A, ga.B[z], ga.bias[z], ga.C[z], nullptr, nullptr, mblk * 128, nblk * 128);
}

__global__ __launch_bounds__(256) void gemm_out(const u16* __restrict__ A, const u16* __restrict__ Bw,
                                                const float* __restrict__ bias, float* __restrict__ C) {
  const int lin = blockIdx.x;                    // 0..511
  const int wid = (lin & 7) * 64 + (lin >> 3);   // bijective: 512 = 8*64
  const int mblk = wid >> 3, nblk = wid & 7;
  gemm_body(A, Bw, bias, nullptr, C, nullptr, mblk * 128, nblk * 128);
}

// ---------------- Flash attention (swapped-operand, paired q-tiles, 2-phase dbuf) ----------------
// grid: 1024 blocks = 64 (b*h) x 16 pairs; block pj handles q-tiles {pj, 31-pj} -> 33 iters each.
// block: 256 thr, 4 waves; wave w owns q rows [w*16, w*16+16); lane l: q = l&15, g = l>>4.
// S^T = mfma(K, Q); O^T = mfma(V^T, P); lane-local softmax.
// 2-phase pipeline (T3 minimum): stage tile t+1 into buf^1 BEFORE computing buf;
// single __syncthreads per tile (compiler's vmcnt0 drain lands AFTER compute).
__global__ __launch_bounds__(256) void attn_fused(const u16* __restrict__ Qb, const u16* __restrict__ Kb,
                                                  const u16* __restrict__ Vt, u16* __restrict__ Ob) {
  __shared__ __align__(16) u16 k_s[2 * 64 * 64];   // [buf][k][d]
  __shared__ __align__(16) u16 vt_s[2 * 64 * 64];  // [buf][d][k]
  __shared__ __align__(16) u16 p_s[4 * 16 * 64];   // per-wave [q][k]
  const int bid = blockIdx.x;
  const int bh = bid & 63;
  const int pj = bid >> 6;  // 0..15
  const int b = bh >> 4, h = bh & 15;
  const size_t baseQ = (size_t)b * 2048 * 1024 + h * 64;
  const size_t baseV = (size_t)(b * 16 + h) * 131072;  // Vt: [bh][64][2048]
  const int tid = threadIdx.x, w = tid >> 6, l = tid & 63;
  const int g = l >> 4, qi = l & 15;
  const int q_loc = w * 16 + qi;

  // staging geometry (wave-linear LDS dest; swizzled global source chunk)
  const int srow = w * 8 + (l >> 3);
  const int sch0 = (l & 7) ^ SWZ(srow);
  const int sch1 = (l & 7) ^ SWZ(srow + 32);
  // loop-invariant LDS frag offsets (elements)
  int koff[4], pvoff[2], voff[4][2];
#pragma unroll
  for (int nf = 0; nf < 4; ++nf) {
    const int row = nf * 16 + qi;
    koff[nf] = row * 64 + ((g ^ SWZ(row)) << 3);  // st=0; st=1 = ^32 elems
#pragma unroll
    for (int ks = 0; ks < 2; ++ks)
      voff[nf][ks] = row * 64 + (((ks * 4 + g) ^ SWZ(row)) << 3);
  }
#pragma unroll
  for (int ks = 0; ks < 2; ++ks)
    pvoff[ks] = qi * 64 + (((ks * 4 + g) ^ SWZ(qi)) << 3);
  u16* pw = p_s + w * 1024;

  const u16* pK0;
  const u16* pK1;
  const u16* pV0;
  const u16* pV1;
  auto stage = [&](int buf) {
    char* kb = (char*)k_s + buf * 8192;
    char* vb = (char*)vt_s + buf * 8192;
    gload16(pK0, kb + w * 1024);
    gload16(pK1, kb + 4096 + w * 1024);
    gload16(pV0, vb + w * 1024);
    gload16(pV1, vb + 4096 + w * 1024);
    pK0 += 65536; pK1 += 65536; pV0 += 64; pV1 += 64;
  };

  int cur = 0;
  for (int half = 0; half < 2; ++half) {
    const int qt = half ? (31 - pj) : pj;
    const int q0 = qt * 64;
    const int q_glob = q0 + q_loc;

    // Q fragments in registers (B-operand: lane holds Q[q=qi][d = st*32 + g*8 + j])
    half8 qf0, qf1;
    {
      const u16* qp = Qb + baseQ + (size_t)q_glob * 1024 + g * 8;
      qf0 = *(const half8*)(qp);
      qf1 = *(const half8*)(qp + 32);
    }
    pK0 = Kb + baseQ + (size_t)srow * 1024 + sch0 * 8;
    pK1 = Kb + baseQ + (size_t)(srow + 32) * 1024 + sch1 * 8;
    pV0 = Vt + baseV + (size_t)srow * 2048 + sch0 * 8;
    pV1 = Vt + baseV + (size_t)(srow + 32) * 2048 + sch1 * 8;

    f32x4 s[4], o[4] = {};
    float m_r = -INFINITY, l_r = 0.f;

    stage(cur);          // prologue: tile 0 of this half
    __syncthreads();     // drains own vmcnt; all waves' stages visible

    for (int kt = 0; kt <= qt; ++kt) {
      if (kt < qt) stage(cur ^ 1);  // issue-early: next tile in flight during compute
      const u16* kbuf = k_s + cur * 4096;
      const u16* vbuf = vt_s + cur * 4096;
      // QK^T (swapped): s[nf] = S^T[k = nf*16 + g*4 + r][q = qi], log2-domain scale
#pragma unroll
      for (int nf = 0; nf < 4; ++nf) {
        half8 k0 = *(const half8*)(kbuf + koff[nf]);
        half8 k1 = *(const half8*)(kbuf + (koff[nf] ^ 32));
        f32x4 acc = {};
        acc = mfma_f16(k0, qf0, acc);
        acc = mfma_f16(k1, qf1, acc);
        s[nf] = acc * SCL2;
      }
      if (kt == qt) {  // diagonal: causal mask
#pragma unroll
        for (int nf = 0; nf < 4; ++nf) {
          const int kb = nf * 16 + g * 4;
#pragma unroll
          for (int r = 0; r < 4; ++r)
            if (kb + r > q_loc) s[nf][r] = -INFINITY;
        }
      }
      // row max via max3 tree (16 regs here + lanes l^16, l^32)
      float t = fmaxf(fmaxf(fmaxf(s[0][0], s[0][1]), s[0][2]),
                      fmaxf(fmaxf(s[0][3], s[1][0]), s[1][1]));
      t = fmaxf(t, fmaxf(fmaxf(s[1][2], s[1][3]), s[2][0]));
      t = fmaxf(t, fmaxf(fmaxf(s[2][1], s[2][2]), s[2][3]));
      t = fmaxf(t, fmaxf(fmaxf(s[3][0], s[3][1]), s[3][2]));
      t = fmaxf(t, s[3][3]);
      t = fmaxf(t, __shfl_xor(t, 16));
      t = fmaxf(t, __shfl_xor(t, 32));
      // defer-max (T13): only rescale when tile max grows past m_r + 8 (log2 units)
      if (!__all(t <= m_r + 8.f)) {
        const float mn = fmaxf(m_r, t);
        const float al = __builtin_amdgcn_exp2f(m_r - mn);
        l_r *= al;
#pragma unroll
        for (int nf = 0; nf < 4; ++nf) o[nf] *= al;
        m_r = mn;
      }
      float rs = 0.f;
#pragma unroll
      for (int nf = 0; nf < 4; ++nf) {
#pragma unroll
        for (int r = 0; r < 4; ++r) {
          const float p = __builtin_amdgcn_exp2f(s[nf][r] - m_r);
          s[nf][r] = p;
          rs += p;
        }
      }
      rs += __shfl_xor(rs, 16);
      rs += __shfl_xor(rs, 32);
      l_r += rs;
      // P -> per-wave LDS: 4 consecutive k per nf -> ds_write_b64 (swizzled, packed cvt)
#pragma unroll
      for (int nf = 0; nf < 4; ++nf) {
        const int c = nf * 2 + (g >> 1);
        *(us4*)(pw + qi * 64 + ((c ^ SWZ(qi)) << 3) + (g & 1) * 4) =
            pack4(s[nf][0], s[nf][1], s[nf][2], s[nf][3]);
      }
      // PV (swapped): o[nf] += V^T frag x P frag
#pragma unroll
      for (int ks = 0; ks < 2; ++ks) {
        half8 pf = *(const half8*)(pw + pvoff[ks]);
#pragma unroll
        for (int nf = 0; nf < 4; ++nf) {
          half8 vf = *(const half8*)(vbuf + voff[nf][ks]);
          o[nf] = mfma_f16(vf, pf, o[nf]);
        }
      }
      __syncthreads();  // single sync/tile: drains own prefetch vmcnt AFTER compute
      cur ^= 1;
    }
    // epilogue: O[q][d], 4 consecutive d per nf -> ushort4 store
    const float inv = 1.f / l_r;
    u16* op = Ob + (size_t)(b * 2048 + q_glob) * 1024 + h * 64 + g * 4;
#pragma unroll
    for (int nf = 0; nf < 4; ++nf)
      *(us4*)(op + nf * 16) =
          pack4(o[nf][0] * inv, o[nf][1] * inv, o[nf][2] * inv, o[nf][3] * inv);
  }
}

extern "C" void kernel_launch(void* const* d_in, const int* in_sizes, int n_in,
                              void* d_out, int out_size, void* d_ws, size_t ws_size,
                              hipStream_t stream) {
  (void)in_sizes; (void)n_in; (void)out_size; (void)ws_size;
  const float* x  = (const float*)d_in[0];
  const float* Wq = (const float*)d_in[1];
  const float* bq = (const float*)d_in[2];
  const float* Wk = (const float*)d_in[3];
  const float* bk = (const float*)d_in[4];
  const float* Wv = (const float*)d_in[5];
  const float* bv = (const float*)d_in[6];
  const float* Wo = (const float*)d_in[7];
  const float* bo = (const float*)d_in[8];

  u16* xb = (u16*)d_ws;                       // 8192*1024 f16 (reused as attn-out later)
  u16* wq = xb + (size_t)8192 * 1024;
  u16* wk = wq + 1024 * 1024;
  u16* wv = wk + 1024 * 1024;
  u16* wo = wv + 1024 * 1024;
  u16* Qb = wo + 1024 * 1024;
  u16* Kb = Qb + (size_t)8192 * 1024;
  u16* Vt = Kb + (size_t)8192 * 1024;         // [b*16+h][64][2048]
  u16* Ab = xb;                               // alias: x_f16 dead after QKV gemm

  cvt_f32_f16<<<4096, 256, 0, stream>>>(x, xb, 1048576);
  cvt_f32_f16<<<512, 256, 0, stream>>>(Wq, wq, 131072);
  cvt_f32_f16<<<512, 256, 0, stream>>>(Wk, wk, 131072);
  cvt_f32_f16<<<512, 256, 0, stream>>>(Wv, wv, 131072);
  cvt_f32_f16<<<512, 256, 0, stream>>>(Wo, wo, 131072);

  QkvArgs ga;
  ga.B[0] = wq; ga.B[1] = wk; ga.B[2] = wv;
  ga.bias[0] = bq; ga.bias[1] = bk; ga.bias[2] = bv;
  ga.C[0] = Qb; ga.C[1] = Kb; ga.C[2] = Vt;
  gemm_qkv<<<1536, 256, 0, stream>>>(xb, ga);

  attn_fused<<<1024, 256, 0, stream>>>(Qb, Kb, Vt, Ab);

  gemm_out<<<512, 256, 0, stream>>>(Ab, wo, bo, (float*)d_out);
}

// Round 7
// 294.215 us; speedup vs baseline: 1.0122x; 1.0122x over previous
//
#include <hip/hip_runtime.h>
#include <hip/hip_fp16.h>

// CausalSelfAttention: B=4 S=2048 D=1024 H=16 HD=64, scale = HD^0.25 (quirk), f32 io.
// Pipeline: cvt(f32->f16) -> fused QKV gemm (V written transposed [b][h][d][s])
//           -> flash attention (swapped-operand, paired q-tiles, 2-phase LDS dbuf)
//           -> output gemm (f32 out + bias).
// R7: GEMMs rebuilt as 256x128 tile, BK=64, 512thr/8wave, stage-early drain-late,
//     1 barrier/tile, frag reuse, SWZ LDS swizzle, XCD-chunked grid, setprio (T5).

typedef unsigned short u16;
typedef unsigned int u32;
typedef _Float16 half8 __attribute__((ext_vector_type(8)));
typedef float f32x4 __attribute__((ext_vector_type(4)));
typedef unsigned short ushort8 __attribute__((ext_vector_type(8)));
typedef unsigned short us4 __attribute__((ext_vector_type(4)));
typedef unsigned int u32x2 __attribute__((ext_vector_type(2)));

#define SCL2 4.0816663172343815f /* 64^0.25 * log2(e) */
#define SWZ(r) ((((r) ^ ((r) >> 3))) & 7)

__device__ __forceinline__ u16 f2h(float f) {
  return __half_as_ushort(__float2half(f));
}

// packed f32->f16 (rtz) x4 -> 8 bytes
__device__ __forceinline__ us4 pack4(float a, float b, float c, float d) {
  u32x2 t;
  t[0] = __builtin_bit_cast(u32, __builtin_amdgcn_cvt_pkrtz(a, b));
  t[1] = __builtin_bit_cast(u32, __builtin_amdgcn_cvt_pkrtz(c, d));
  return __builtin_bit_cast(us4, t);
}

__device__ __forceinline__ void gload16(const void* gsrc, void* ldst) {
  typedef __attribute__((address_space(1))) const void glob_t;
  typedef __attribute__((address_space(3))) void lds_t;
  __builtin_amdgcn_global_load_lds((glob_t*)gsrc, (lds_t*)ldst, 16, 0, 0);
}

__device__ __forceinline__ f32x4 mfma_f16(half8 a, half8 b, f32x4 c) {
  return __builtin_amdgcn_mfma_f32_16x16x32_f16(a, b, c, 0, 0, 0);
}

// ---------------- f32 -> f16 convert, 8 elements/thread ----------------
__global__ __launch_bounds__(256) void cvt_f32_f16(const float* __restrict__ in,
                                                   u16* __restrict__ out, int n8) {
  int i = blockIdx.x * 256 + threadIdx.x;
  if (i >= n8) return;
  const float4* p = (const float4*)in + (size_t)i * 2;
  float4 a = p[0], b = p[1];
  ushort8 v;
  v[0] = f2h(a.x); v[1] = f2h(a.y); v[2] = f2h(a.z); v[3] = f2h(a.w);
  v[4] = f2h(b.x); v[5] = f2h(b.y); v[6] = f2h(b.z); v[7] = f2h(b.w);
  *(ushort8*)(out + (size_t)i * 8) = v;
}

// ---------------- GEMM: C[M=8192,N=1024] = A[M,K=1024] * Bw[N,K]^T + bias ----------------
// 256x128 tile, BK=64, 512 threads = 8 waves (2M x 4N), per-wave 128x32 (acc[8][2]).
// 2-phase LDS dbuf, ONE barrier per K-tile; all 6 stage-loads for tile t+1 issued at
// the top of tile t (drain at the tile-end __syncthreads has full-tile compute cover).
// LDS rows are 64 f16 = 8 chunks of 8; chunk c of row r stored at c^SWZ(r) (0-conflict,
// verified R6). Epilogues: Ch f16 [tok][1024]; Cf f32; Vtp f16 [b*16+h][64][2048].
__device__ __forceinline__ void gemm_body(const u16* __restrict__ A, const u16* __restrict__ Bw,
                                          const float* __restrict__ bias,
                                          u16* __restrict__ Ch, float* __restrict__ Cf,
                                          u16* __restrict__ Vtp, int m0, int n0) {
  __shared__ __align__(16) u16 sA[2][256 * 64];
  __shared__ __align__(16) u16 sB[2][128 * 64];
  const int tid = threadIdx.x, w = tid >> 6, l = tid & 63;
  const int g = l >> 4, fr = l & 15;
  const int wm = (w >> 2) * 128, wn = (w & 3) * 32;
  f32x4 acc[8][2] = {};
  // staging sources: round i covers rows [i*64, +64); wave w rows [w*8,+8); lane row l>>3
  const int srow8 = w * 8 + (l >> 3);
  size_t aoff[4], boff[2];
#pragma unroll
  for (int i = 0; i < 4; ++i) {
    const int row = i * 64 + srow8;
    aoff[i] = (size_t)(m0 + row) * 1024 + ((l & 7) ^ SWZ(row)) * 8;
  }
#pragma unroll
  for (int i = 0; i < 2; ++i) {
    const int row = i * 64 + srow8;
    boff[i] = (size_t)(n0 + row) * 1024 + ((l & 7) ^ SWZ(row)) * 8;
  }
  const int ldst = w * 1024 + l * 16;  // byte offset within an 8KB round
  auto stage = [&](int buf, int k0) {
    char* ab = (char*)sA[buf];
    char* bb = (char*)sB[buf];
#pragma unroll
    for (int i = 0; i < 4; ++i) gload16(A + aoff[i] + k0, ab + i * 8192 + ldst);
#pragma unroll
    for (int i = 0; i < 2; ++i) gload16(Bw + boff[i] + k0, bb + i * 8192 + ldst);
  };
  // loop-invariant frag LDS offsets (elements): chunk q of row r lives at q^SWZ(r)
  int aofr[8][2], bofr[2][2];
#pragma unroll
  for (int mf = 0; mf < 8; ++mf) {
    const int row = wm + mf * 16 + fr;
#pragma unroll
    for (int kk = 0; kk < 2; ++kk)
      aofr[mf][kk] = row * 64 + (((kk * 4 + g) ^ SWZ(row)) << 3);
  }
#pragma unroll
  for (int nf = 0; nf < 2; ++nf) {
    const int row = wn + nf * 16 + fr;
#pragma unroll
    for (int kk = 0; kk < 2; ++kk)
      bofr[nf][kk] = row * 64 + (((kk * 4 + g) ^ SWZ(row)) << 3);
  }

  stage(0, 0);
  __syncthreads();
  for (int t = 0; t < 16; ++t) {
    const int cur = t & 1;
    if (t < 15) stage(cur ^ 1, (t + 1) * 64);  // issue-early: full tile of cover
    const u16* sa = sA[cur];
    const u16* sb = sB[cur];
    half8 bf[2][2];
#pragma unroll
    for (int nf = 0; nf < 2; ++nf)
#pragma unroll
      for (int kk = 0; kk < 2; ++kk)
        bf[nf][kk] = *(const half8*)&sb[bofr[nf][kk]];
#pragma unroll
    for (int mh = 0; mh < 2; ++mh) {
      half8 af[4][2];
#pragma unroll
      for (int mq = 0; mq < 4; ++mq)
#pragma unroll
        for (int kk = 0; kk < 2; ++kk)
          af[mq][kk] = *(const half8*)&sa[aofr[mh * 4 + mq][kk]];
      __builtin_amdgcn_s_setprio(1);
#pragma unroll
      for (int mq = 0; mq < 4; ++mq)
#pragma unroll
        for (int nf = 0; nf < 2; ++nf)
#pragma unroll
          for (int kk = 0; kk < 2; ++kk)
            acc[mh * 4 + mq][nf] = mfma_f16(af[mq][kk], bf[nf][kk], acc[mh * 4 + mq][nf]);
      __builtin_amdgcn_s_setprio(0);
    }
    __syncthreads();  // single sync/tile: drains own prefetch AFTER full-tile compute
  }

  if (Vtp) {
    // V^T epilogue: Vt[(b*16+h)][d][s], 4 consecutive s (r=0..3) -> ushort4 store.
#pragma unroll
    for (int nf = 0; nf < 2; ++nf) {
      const int col = n0 + wn + nf * 16 + fr;  // d_model = h*64+d
      const float bv = bias[col];
#pragma unroll
      for (int mf = 0; mf < 8; ++mf) {
        const int row = m0 + wm + mf * 16 + g * 4;  // token = b*2048+s
        us4 v;
#pragma unroll
        for (int r = 0; r < 4; ++r) v[r] = f2h(acc[mf][nf][r] + bv);
        *(us4*)(Vtp + (size_t)((row >> 11) * 16 + (col >> 6)) * 131072 +
                (size_t)(col & 63) * 2048 + (row & 2047)) = v;
      }
    }
  } else {
#pragma unroll
    for (int nf = 0; nf < 2; ++nf) {
      const int col = n0 + wn + nf * 16 + fr;
      const float bv = bias[col];
#pragma unroll
      for (int mf = 0; mf < 8; ++mf) {
#pragma unroll
        for (int r = 0; r < 4; ++r) {
          const int row = m0 + wm + mf * 16 + g * 4 + r;
          float v = acc[mf][nf][r] + bv;
          if (Cf) Cf[(size_t)row * 1024 + col] = v;
          else    Ch[(size_t)row * 1024 + col] = f2h(v);
        }
      }
    }
  }
}

struct QkvArgs {
  const u16* B[3];
  const float* bias[3];
  u16* C[3];
};

// XCD-chunked swizzle (T1): xcd = lin&7 (dispatch round-robin); each XCD gets a
// contiguous chunk, m-panel major: the 24 blocks (8 n x 3 z) sharing one 256-row
// A-panel run on ONE XCD's L2 (4 panels x 512KB = 2MB per XCD).
__global__ __launch_bounds__(512, 2) void gemm_qkv(const u16* __restrict__ A, QkvArgs ga) {
  const int lin = blockIdx.x;                    // 0..767
  const int wid = (lin & 7) * 96 + (lin >> 3);   // bijective: 768 = 8*96
  const int mblk = wid / 24;                     // 0..31
  const int rem = wid - mblk * 24;
  const int z = rem >> 3, nblk = rem & 7;
  if (z == 2) gemm_body(A, ga.B[2], ga.bias[2], nullptr, nullptr, ga.C[2], mblk * 256, nblk * 128);
  else        gemm_body(A, ga.B[z], ga.bias[z], ga.C[z], nullptr, nullptr, mblk * 256, nblk * 128);
}

__global__ __launch_bounds__(512, 2) void gemm_out(const u16* __restrict__ A, const u16* __restrict__ Bw,
                                                   const float* __restrict__ bias, float* __restrict__ C) {
  const int lin = blockIdx.x;                    // 0..255
  const int wid = (lin & 7) * 32 + (lin >> 3);   // bijective: 256 = 8*32
  const int mblk = wid >> 3, nblk = wid & 7;
  gemm_body(A, Bw, bias, nullptr, C, nullptr, mblk * 256, nblk * 128);
}

// ---------------- Flash attention (swapped-operand, paired q-tiles, 2-phase dbuf) ----------------
// grid: 1024 blocks = 64 (b*h) x 16 pairs; block pj handles q-tiles {pj, 31-pj} -> 33 iters each.
// block: 256 thr, 4 waves; wave w owns q rows [w*16, w*16+16); lane l: q = l&15, g = l>>4.
// S^T = mfma(K, Q); O^T = mfma(V^T, P); lane-local softmax.
// 2-phase pipeline (T3 minimum): stage tile t+1 into buf^1 BEFORE computing buf;
// single __syncthreads per tile (compiler's vmcnt0 drain lands AFTER compute).
__global__ __launch_bounds__(256) void attn_fused(const u16* __restrict__ Qb, const u16* __restrict__ Kb,
                                                  const u16* __restrict__ Vt, u16* __restrict__ Ob) {
  __shared__ __align__(16) u16 k_s[2 * 64 * 64];   // [buf][k][d]
  __shared__ __align__(16) u16 vt_s[2 * 64 * 64];  // [buf][d][k]
  __shared__ __align__(16) u16 p_s[4 * 16 * 64];   // per-wave [q][k]
  const int bid = blockIdx.x;
  const int bh = bid & 63;
  const int pj = bid >> 6;  // 0..15
  const int b = bh >> 4, h = bh & 15;
  const size_t baseQ = (size_t)b * 2048 * 1024 + h * 64;
  const size_t baseV = (size_t)(b * 16 + h) * 131072;  // Vt: [bh][64][2048]
  const int tid = threadIdx.x, w = tid >> 6, l = tid & 63;
  const int g = l >> 4, qi = l & 15;
  const int q_loc = w * 16 + qi;

  // staging geometry (wave-linear LDS dest; swizzled global source chunk)
  const int srow = w * 8 + (l >> 3);
  const int sch0 = (l & 7) ^ SWZ(srow);
  const int sch1 = (l & 7) ^ SWZ(srow + 32);
  // loop-invariant LDS frag offsets (elements)
  int koff[4], pvoff[2], voff[4][2];
#pragma unroll
  for (int nf = 0; nf < 4; ++nf) {
    const int row = nf * 16 + qi;
    koff[nf] = row * 64 + ((g ^ SWZ(row)) << 3);  // st=0; st=1 = ^32 elems
#pragma unroll
    for (int ks = 0; ks < 2; ++ks)
      voff[nf][ks] = row * 64 + (((ks * 4 + g) ^ SWZ(row)) << 3);
  }
#pragma unroll
  for (int ks = 0; ks < 2; ++ks)
    pvoff[ks] = qi * 64 + (((ks * 4 + g) ^ SWZ(qi)) << 3);
  u16* pw = p_s + w * 1024;

  const u16* pK0;
  const u16* pK1;
  const u16* pV0;
  const u16* pV1;
  auto stage = [&](int buf) {
    char* kb = (char*)k_s + buf * 8192;
    char* vb = (char*)vt_s + buf * 8192;
    gload16(pK0, kb + w * 1024);
    gload16(pK1, kb + 4096 + w * 1024);
    gload16(pV0, vb + w * 1024);
    gload16(pV1, vb + 4096 + w * 1024);
    pK0 += 65536; pK1 += 65536; pV0 += 64; pV1 += 64;
  };

  int cur = 0;
  for (int half = 0; half < 2; ++half) {
    const int qt = half ? (31 - pj) : pj;
    const int q0 = qt * 64;
    const int q_glob = q0 + q_loc;

    // Q fragments in registers (B-operand: lane holds Q[q=qi][d = st*32 + g*8 + j])
    half8 qf0, qf1;
    {
      const u16* qp = Qb + baseQ + (size_t)q_glob * 1024 + g * 8;
      qf0 = *(const half8*)(qp);
      qf1 = *(const half8*)(qp + 32);
    }
    pK0 = Kb + baseQ + (size_t)srow * 1024 + sch0 * 8;
    pK1 = Kb + baseQ + (size_t)(srow + 32) * 1024 + sch1 * 8;
    pV0 = Vt + baseV + (size_t)srow * 2048 + sch0 * 8;
    pV1 = Vt + baseV + (size_t)(srow + 32) * 2048 + sch1 * 8;

    f32x4 s[4], o[4] = {};
    float m_r = -INFINITY, l_r = 0.f;

    stage(cur);          // prologue: tile 0 of this half
    __syncthreads();     // drains own vmcnt; all waves' stages visible

    for (int kt = 0; kt <= qt; ++kt) {
      if (kt < qt) stage(cur ^ 1);  // issue-early: next tile in flight during compute
      const u16* kbuf = k_s + cur * 4096;
      const u16* vbuf = vt_s + cur * 4096;
      // QK^T (swapped): s[nf] = S^T[k = nf*16 + g*4 + r][q = qi], log2-domain scale
#pragma unroll
      for (int nf = 0; nf < 4; ++nf) {
        half8 k0 = *(const half8*)(kbuf + koff[nf]);
        half8 k1 = *(const half8*)(kbuf + (koff[nf] ^ 32));
        f32x4 acc = {};
        acc = mfma_f16(k0, qf0, acc);
        acc = mfma_f16(k1, qf1, acc);
        s[nf] = acc * SCL2;
      }
      if (kt == qt) {  // diagonal: causal mask
#pragma unroll
        for (int nf = 0; nf < 4; ++nf) {
          const int kb = nf * 16 + g * 4;
#pragma unroll
          for (int r = 0; r < 4; ++r)
            if (kb + r > q_loc) s[nf][r] = -INFINITY;
        }
      }
      // row max via max3 tree (16 regs here + lanes l^16, l^32)
      float t = fmaxf(fmaxf(fmaxf(s[0][0], s[0][1]), s[0][2]),
                      fmaxf(fmaxf(s[0][3], s[1][0]), s[1][1]));
      t = fmaxf(t, fmaxf(fmaxf(s[1][2], s[1][3]), s[2][0]));
      t = fmaxf(t, fmaxf(fmaxf(s[2][1], s[2][2]), s[2][3]));
      t = fmaxf(t, fmaxf(fmaxf(s[3][0], s[3][1]), s[3][2]));
      t = fmaxf(t, s[3][3]);
      t = fmaxf(t, __shfl_xor(t, 16));
      t = fmaxf(t, __shfl_xor(t, 32));
      // defer-max (T13): only rescale when tile max grows past m_r + 8 (log2 units)
      if (!__all(t <= m_r + 8.f)) {
        const float mn = fmaxf(m_r, t);
        const float al = __builtin_amdgcn_exp2f(m_r - mn);
        l_r *= al;
#pragma unroll
        for (int nf = 0; nf < 4; ++nf) o[nf] *= al;
        m_r = mn;
      }
      float rs = 0.f;
#pragma unroll
      for (int nf = 0; nf < 4; ++nf) {
#pragma unroll
        for (int r = 0; r < 4; ++r) {
          const float p = __builtin_amdgcn_exp2f(s[nf][r] - m_r);
          s[nf][r] = p;
          rs += p;
        }
      }
      rs += __shfl_xor(rs, 16);
      rs += __shfl_xor(rs, 32);
      l_r += rs;
      // P -> per-wave LDS: 4 consecutive k per nf -> ds_write_b64 (swizzled, packed cvt)
#pragma unroll
      for (int nf = 0; nf < 4; ++nf) {
        const int c = nf * 2 + (g >> 1);
        *(us4*)(pw + qi * 64 + ((c ^ SWZ(qi)) << 3) + (g & 1) * 4) =
            pack4(s[nf][0], s[nf][1], s[nf][2], s[nf][3]);
      }
      // PV (swapped): o[nf] += V^T frag x P frag
#pragma unroll
      for (int ks = 0; ks < 2; ++ks) {
        half8 pf = *(const half8*)(pw + pvoff[ks]);
#pragma unroll
        for (int nf = 0; nf < 4; ++nf) {
          half8 vf = *(const half8*)(vbuf + voff[nf][ks]);
          o[nf] = mfma_f16(vf, pf, o[nf]);
        }
      }
      __syncthreads();  // single sync/tile: drains own prefetch vmcnt AFTER compute
      cur ^= 1;
    }
    // epilogue: O[q][d], 4 consecutive d per nf -> ushort4 store
    const float inv = 1.f / l_r;
    u16* op = Ob + (size_t)(b * 2048 + q_glob) * 1024 + h * 64 + g * 4;
#pragma unroll
    for (int nf = 0; nf < 4; ++nf)
      *(us4*)(op + nf * 16) =
          pack4(o[nf][0] * inv, o[nf][1] * inv, o[nf][2] * inv, o[nf][3] * inv);
  }
}

extern "C" void kernel_launch(void* const* d_in, const int* in_sizes, int n_in,
                              void* d_out, int out_size, void* d_ws, size_t ws_size,
                              hipStream_t stream) {
  (void)in_sizes; (void)n_in; (void)out_size; (void)ws_size;
  const float* x  = (const float*)d_in[0];
  const float* Wq = (const float*)d_in[1];
  const float* bq = (const float*)d_in[2];
  const float* Wk = (const float*)d_in[3];
  const float* bk = (const float*)d_in[4];
  const float* Wv = (const float*)d_in[5];
  const float* bv = (const float*)d_in[6];
  const float* Wo = (const float*)d_in[7];
  const float* bo = (const float*)d_in[8];

  u16* xb = (u16*)d_ws;                       // 8192*1024 f16 (reused as attn-out later)
  u16* wq = xb + (size_t)8192 * 1024;
  u16* wk = wq + 1024 * 1024;
  u16* wv = wk + 1024 * 1024;
  u16* wo = wv + 1024 * 1024;
  u16* Qb = wo + 1024 * 1024;
  u16* Kb = Qb + (size_t)8192 * 1024;
  u16* Vt = Kb + (size_t)8192 * 1024;         // [b*16+h][64][2048]
  u16* Ab = xb;                               // alias: x_f16 dead after QKV gemm

  cvt_f32_f16<<<4096, 256, 0, stream>>>(x, xb, 1048576);
  cvt_f32_f16<<<512, 256, 0, stream>>>(Wq, wq, 131072);
  cvt_f32_f16<<<512, 256, 0, stream>>>(Wk, wk, 131072);
  cvt_f32_f16<<<512, 256, 0, stream>>>(Wv, wv, 131072);
  cvt_f32_f16<<<512, 256, 0, stream>>>(Wo, wo, 131072);

  QkvArgs ga;
  ga.B[0] = wq; ga.B[1] = wk; ga.B[2] = wv;
  ga.bias[0] = bq; ga.bias[1] = bk; ga.bias[2] = bv;
  ga.C[0] = Qb; ga.C[1] = Kb; ga.C[2] = Vt;
  gemm_qkv<<<768, 512, 0, stream>>>(xb, ga);

  attn_fused<<<1024, 256, 0, stream>>>(Qb, Kb, Vt, Ab);

  gemm_out<<<256, 512, 0, stream>>>(Ab, wo, bo, (float*)d_out);
}